// Round 7
// baseline (172.780 us; speedup 1.0000x reference)
//
#include <hip/hip_runtime.h>

#define FD  128
#define NN  2048

// workspace layout (float elements). In fused mode m2 never materialized
// (lives in regs between the m2 GEMM and the fused BN epilogue).
#define OFF_X     0            // x[n][f] (BN-applied, updated per layer)
#define OFF_QS    262144       // qs[r][n]           2*2048
#define OFF_KS    266240       // ks[r][n]           2*2048
#define OFF_SUMS  270336       // l*2048 + slot*256 + {0:sum,128:sumsq}, 8 slots
#define OFF_CTR   276480       // 3 arrival counters (int), one per layer
#define OFF_LWT   276608       // l*32768 + c*128 + o   (lin_W transposed)
#define OFF_QH    374912       // qhat[l][r][f] = sum_o W[l,r,f,o]*q[l,o]  768
#define OFF_KH    375680       // khat[l][r][f]                            768
#define OFF_M2    376448       // m2[n][f] (fallback path only)

// XCD-affine swizzle for 512 blocks: bid&7 = XCD; graph = XCD pair; 128
// slots x 4 rows per graph.
__device__ __forceinline__ int swizzle_n0(int bid) {
    int g    = (bid & 7) >> 1;                 // graph 0..3
    int slot = ((bid >> 3) << 1) | (bid & 1);  // 0..127
    return g*512 + slot*4;                     // first of 4 rows
}

// layer-0 qs/ks via full proj in registers. No proj store.
__device__ __forceinline__ void qsks0(
    const float* __restrict__ W, const float* __restrict__ qv,
    const float* __restrict__ kv, float* __restrict__ ws,
    int n0, int t, const float (*xs)[FD],
    float (*redp)[256], float* red)
{
    int kh = t >> 8, tp = t & 255;
    int rsel = tp >> 7, o = tp & 127;
    const float* Wl = W + ((size_t)rsel*FD)*FD + o;
    float acc[4];
#pragma unroll
    for (int r = 0; r < 4; r++) acc[r] = 0.f;
    int kbase = kh * 64;
#pragma unroll
    for (int kk = 0; kk < 64; kk += 4) {
        int k4 = kbase + kk;
        float w0 = Wl[(k4+0)*FD], w1 = Wl[(k4+1)*FD];
        float w2 = Wl[(k4+2)*FD], w3 = Wl[(k4+3)*FD];
#pragma unroll
        for (int r = 0; r < 4; r++) {
            float4 xq = *(const float4*)&xs[r][k4];
            acc[r] += xq.x*w0 + xq.y*w1 + xq.z*w2 + xq.w*w3;
        }
    }
    if (kh == 1) {
#pragma unroll
        for (int r = 0; r < 4; r++) redp[r][tp] = acc[r];
    }
    __syncthreads();
    if (t < 256) {
#pragma unroll
        for (int r = 0; r < 4; r++) acc[r] += redp[r][tp];
        float qq = qv[o], kq = kv[o];
        int lane = t & 63, w = t >> 6;
#pragma unroll
        for (int r = 0; r < 4; r++) {
            float vq = acc[r]*qq, vk = acc[r]*kq;
            for (int off = 32; off; off >>= 1) {
                vq += __shfl_xor(vq, off, 64);
                vk += __shfl_xor(vk, off, 64);
            }
            if (lane == 0) { red[w*8 + r*2] = vq; red[w*8 + r*2 + 1] = vk; }
        }
    }
    __syncthreads();
    if (t < 16) {
        int r = t & 3, rs = (t >> 2) & 1, wh = t >> 3;
        float v = red[(rs*2)*8 + r*2 + wh] + red[(rs*2 + 1)*8 + r*2 + wh];
        if (wh == 0) ws[OFF_QS + rs*NN + n0 + r] = v;
        else         ws[OFF_KS + rs*NN + n0 + r] = v;
    }
}

// ---------------- k_pre: transpose + qs/ks(0) + linWT + qhat/khat + zero sums/ctrs
__global__ __launch_bounds__(512, 4) void k_pre(
    const float* __restrict__ d0, const float* __restrict__ d1,
    const float* __restrict__ W,  const float* __restrict__ qv,
    const float* __restrict__ kv, const float* __restrict__ linW,
    float* __restrict__ ws)
{
    int bid = blockIdx.x, t = threadIdx.x;
    if (bid >= 512) {
        if (bid < 536) {               // linWT[l][c][o] = lin_W[l][o][c]
            int vb = bid - 512;        // 0..23
#pragma unroll
            for (int i = 0; i < 8; i++) {
                int e = vb*4096 + i*512 + t;   // 0..98303
                int l = e >> 15, rem = e & 32767;
                int o = rem >> 8, c = rem & 255;
                ws[OFF_LWT + l*32768 + c*FD + o] = linW[e];
            }
        } else {                       // bid 536: zero sums+ctrs, qhat/khat
            for (int i = t; i < 6144 + 128; i += 512) ws[OFF_SUMS + i] = 0.f;
#pragma unroll
            for (int ii = 0; ii < 3; ii++) {
                int e = ii*512 + t;            // 0..1535
                int sel = e & 1, idx = e >> 1; // idx = l*256 + r*128 + f
                const float* wrow = W + (size_t)idx*FD;
                int l = idx >> 8;
                const float* vvec = sel ? (kv + l*FD) : (qv + l*FD);
                float acc = 0.f;
                for (int o = 0; o < FD; o++) acc += wrow[o]*vvec[o];
                ws[(sel ? OFF_KH : OFF_QH) + idx] = acc;
            }
        }
        return;
    }
    __shared__ __attribute__((aligned(16))) float xs[4][FD];
    __shared__ float redp[4][256];
    __shared__ float red[32];
    int n0 = swizzle_n0(bid);
    {
        int row = t >> 7, f = t & 127;
        int n = n0 + row, gg = n >> 9, ii = n & 511;
        float v = (ii < 256) ? d0[gg*32768 + f*256 + ii]
                             : d1[gg*32768 + f*256 + (ii - 256)];
        xs[row][f] = v;
        ws[OFF_X + (size_t)n*FD + f] = v;
    }
    __syncthreads();
    qsks0(W, qv, kv, ws, n0, t, xs, redp, red);
}

// ---------------- k_attn<MODE>: stats + att-sum + agg GEMM + m1 + m2 GEMM.
// MODE 0: fused epilogue writes x_{l+1} + qs/ks(l+1)  [cooperative launch]
// MODE 1: fused epilogue writes final output          [cooperative launch]
// MODE 2: no epilogue; write m2 to global (fallback, normal launch)
// Intra-kernel sync (MODE 0/1): atomics-only ticket barrier — NO grid.sync,
// so no device-scope L2 flush (R2 lesson). Only SUMS crosses blocks inside
// the kernel and is read back via atomic RMW (coherence-point safe).
template<int MODE>
__global__ __launch_bounds__(512, 4) void k_attn(
    const float* __restrict__ Wg,    const float* __restrict__ convb,
    const float* __restrict__ linb,  const float* __restrict__ gamma,
    const float* __restrict__ beta,  float* __restrict__ out,
    float* __restrict__ ws, int l)
{
    __shared__ __attribute__((aligned(16))) float att[4*512];    // 8K
    __shared__ __attribute__((aligned(16))) float redB[8*4*128]; // 16K
    __shared__ __attribute__((aligned(16))) float hgc[4*256];    // hg -> cat 4K
    __shared__ float sml[4][2], sls[4][2];
    __shared__ float r1[FD], r2[FD];
    __shared__ float sc2[FD], sh2[FD];
    __shared__ float redq[4][8];

    int bid = blockIdx.x, t = threadIdx.x;
    int dstbase = swizzle_n0(bid);
    int g = dstbase >> 9, dloc0 = dstbase & 511;
    int Gd = (dloc0 >= 256) ? 1 : 0;

    // stats: 8 waves, 2 per dst row (half src-range each), merged via LDS
    {
        int w = t >> 6, p = t & 63;
        int d = w >> 1, h = w & 1;
        int dloc = dloc0 + d;
        float q0 = ws[OFF_QS + dstbase + d];
        float q1 = ws[OFF_QS + NN + dstbase + d];
        float sc[4];
#pragma unroll
        for (int j = 0; j < 4; j++) {
            int s = h*256 + p + j*64;
            int ts = (s < 256) ? Gd : 1 - Gd;
            float a = (ts ? q1 : q0) + ws[OFF_KS + ts*NN + g*512 + s];
            a = a > 0.f ? a : 0.2f*a;
            sc[j] = (s == dloc) ? -1e30f : a;
        }
        float lm = fmaxf(fmaxf(sc[0], sc[1]), fmaxf(sc[2], sc[3]));
        for (int off = 32; off; off >>= 1) lm = fmaxf(lm, __shfl_xor(lm, off, 64));
        float ex[4], lsum = 0.f;
#pragma unroll
        for (int j = 0; j < 4; j++) { ex[j] = __expf(sc[j] - lm); lsum += ex[j]; }
        for (int off = 32; off; off >>= 1) lsum += __shfl_xor(lsum, off, 64);
#pragma unroll
        for (int j = 0; j < 4; j++) att[d*512 + h*256 + p + j*64] = ex[j];
        if (p == 0) { sml[d][h] = lm; sls[d][h] = lsum; }
    }
    __syncthreads();
    // normalize across the two halves + zero r1/r2
    {
        int d = t >> 7, s4 = (t & 127) * 4;
        int h = (s4 >= 256) ? 1 : 0;
        float m0 = sml[d][0], m1 = sml[d][1];
        float M = fmaxf(m0, m1);
        float denom = sls[d][0]*__expf(m0 - M) + sls[d][1]*__expf(m1 - M) + 1e-16f;
        float fac = __expf(sml[d][h] - M) / denom;
        float4 a4 = *(float4*)&att[d*512 + s4];
        a4.x *= fac; a4.y *= fac; a4.z *= fac; a4.w *= fac;
        *(float4*)&att[d*512 + s4] = a4;
        if (t < 128) r1[t] = 0.f;
        else if (t < 256) r2[t - 128] = 0.f;
    }
    __syncthreads();

    // phase B: att-weighted sums of x by src half; 2-deep register pipeline.
    int f4 = t & 31, sq = t >> 5;
    float acc[4][4];
#pragma unroll
    for (int d2 = 0; d2 < 4; d2++)
#pragma unroll
        for (int j = 0; j < 4; j++) acc[d2][j] = 0.f;
    {
        const float* xp = ws + OFF_X + (size_t)(g*512)*FD + f4*4;
        int s0 = sq * 32;
        float4 bufA[4], bufB[4];
#pragma unroll
        for (int u = 0; u < 4; u++) bufA[u] = *(const float4*)&xp[(size_t)(s0+u)*FD];
#pragma unroll
        for (int ii = 0; ii < 8; ii++) {
            const float4* cur = (ii & 1) ? bufB : bufA;   // static under unroll
            float4*       nxt = (ii & 1) ? bufA : bufB;
            if (ii < 7) {
#pragma unroll
                for (int u = 0; u < 4; u++)
                    nxt[u] = *(const float4*)&xp[(size_t)(s0 + (ii+1)*4 + u)*FD];
            }
#pragma unroll
            for (int u = 0; u < 4; u++) {
                int s = s0 + ii*4 + u;
                float4 v = cur[u];
#pragma unroll
                for (int d2 = 0; d2 < 4; d2++) {
                    float b = att[d2*512 + s];
                    acc[d2][0] += b*v.x; acc[d2][1] += b*v.y;
                    acc[d2][2] += b*v.z; acc[d2][3] += b*v.w;
                }
            }
        }
    }
    // group-split staged reduction: slots 0..3 = src half0, 4..7 = half1
    {
        int slot = (sq & 3) + ((sq >> 3) << 2);
        if (sq & 4) {
#pragma unroll
            for (int d2 = 0; d2 < 4; d2++)
                *(float4*)&redB[(slot*4 + d2)*128 + f4*4] =
                    make_float4(acc[d2][0], acc[d2][1], acc[d2][2], acc[d2][3]);
        }
        __syncthreads();
        if (!(sq & 4)) {
#pragma unroll
            for (int d2 = 0; d2 < 4; d2++) {
                float4 p4 = *(const float4*)&redB[(slot*4 + d2)*128 + f4*4];
                *(float4*)&redB[(slot*4 + d2)*128 + f4*4] =
                    make_float4(acc[d2][0]+p4.x, acc[d2][1]+p4.y, acc[d2][2]+p4.z, acc[d2][3]+p4.w);
            }
        }
        __syncthreads();
    }
    // hg reduce -> hgc = [hg_same | hg_cross]
    {
        int d2 = t >> 7, f = t & 127;
        float hg0 = redB[(0*4+d2)*128+f] + redB[(1*4+d2)*128+f]
                  + redB[(2*4+d2)*128+f] + redB[(3*4+d2)*128+f];
        float hg1 = redB[(4*4+d2)*128+f] + redB[(5*4+d2)*128+f]
                  + redB[(6*4+d2)*128+f] + redB[(7*4+d2)*128+f];
        hgc[d2*256 + f]       = Gd ? hg1 : hg0;   // same-group (rel 0)
        hgc[d2*256 + 128 + f] = Gd ? hg0 : hg1;   // cross-group (rel 1)
    }
    __syncthreads();

    // agg GEMM: [4,256] x Wcat[256,128]
#pragma unroll
    for (int d2 = 0; d2 < 4; d2++)
#pragma unroll
        for (int j = 0; j < 4; j++) acc[d2][j] = 0.f;
    {
        int rel = sq >> 3;
        const float* wp = Wg + ((size_t)((l*2 + rel)*FD) + (sq & 7)*16)*FD + f4*4;
        int c0 = sq * 16;
        float4 wA[4], wB[4];
#pragma unroll
        for (int u = 0; u < 4; u++) wA[u] = *(const float4*)&wp[(size_t)u*FD];
#pragma unroll
        for (int ii = 0; ii < 4; ii++) {
            const float4* cur = (ii & 1) ? wB : wA;
            float4*       nxt = (ii & 1) ? wA : wB;
            if (ii < 3) {
#pragma unroll
                for (int u = 0; u < 4; u++)
                    nxt[u] = *(const float4*)&wp[(size_t)((ii+1)*4 + u)*FD];
            }
#pragma unroll
            for (int u = 0; u < 4; u++) {
                int c = c0 + ii*4 + u;
                float4 w4 = cur[u];
#pragma unroll
                for (int d2 = 0; d2 < 4; d2++) {
                    float cv = hgc[d2*256 + c];
                    acc[d2][0] += cv*w4.x; acc[d2][1] += cv*w4.y;
                    acc[d2][2] += cv*w4.z; acc[d2][3] += cv*w4.w;
                }
            }
        }
    }
    if (sq >= 8) {
#pragma unroll
        for (int d2 = 0; d2 < 4; d2++)
            *(float4*)&redB[((sq - 8)*4 + d2)*128 + f4*4] =
                make_float4(acc[d2][0], acc[d2][1], acc[d2][2], acc[d2][3]);
    }
    __syncthreads();
    if (sq < 8) {
#pragma unroll
        for (int d2 = 0; d2 < 4; d2++) {
            float4 p4 = *(const float4*)&redB[(sq*4 + d2)*128 + f4*4];
            *(float4*)&redB[(sq*4 + d2)*128 + f4*4] =
                make_float4(acc[d2][0]+p4.x, acc[d2][1]+p4.y, acc[d2][2]+p4.z, acc[d2][3]+p4.w);
        }
    }
    __syncthreads();

    // agg reduce -> m1; build cat = [x | m1]; capture x_old in reg
    float xold;
    {
        int d2 = t >> 7, f = t & 127;
        float agg = 0.f;
#pragma unroll
        for (int cc = 0; cc < 8; cc++) agg += redB[(cc*4 + d2)*128 + f];
        float m1v = fmaxf(agg + convb[l*FD + f], 0.f);
        hgc[d2*256 + 128 + f] = m1v;
        xold = ws[OFF_X + (size_t)(dstbase + d2)*FD + f];
        hgc[d2*256 + f] = xold;
    }
    __syncthreads();

    // m2 GEMM: [4,256] x linWT[256,128]
#pragma unroll
    for (int d2 = 0; d2 < 4; d2++)
#pragma unroll
        for (int j = 0; j < 4; j++) acc[d2][j] = 0.f;
    {
        const float* lwt = ws + OFF_LWT + l*32768 + f4*4;
        int c0 = sq * 16;
        float4 wA[4], wB[4];
#pragma unroll
        for (int u = 0; u < 4; u++) wA[u] = *(const float4*)&lwt[(c0+u)*128];
#pragma unroll
        for (int ii = 0; ii < 4; ii++) {
            const float4* cur = (ii & 1) ? wB : wA;
            float4*       nxt = (ii & 1) ? wA : wB;
            if (ii < 3) {
#pragma unroll
                for (int u = 0; u < 4; u++)
                    nxt[u] = *(const float4*)&lwt[(c0 + (ii+1)*4 + u)*128];
            }
#pragma unroll
            for (int u = 0; u < 4; u++) {
                int c = c0 + ii*4 + u;
                float4 w4 = cur[u];
#pragma unroll
                for (int d2 = 0; d2 < 4; d2++) {
                    float cv = hgc[d2*256 + c];
                    acc[d2][0] += cv*w4.x; acc[d2][1] += cv*w4.y;
                    acc[d2][2] += cv*w4.z; acc[d2][3] += cv*w4.w;
                }
            }
        }
    }
    if (sq >= 8) {
#pragma unroll
        for (int d2 = 0; d2 < 4; d2++)
            *(float4*)&redB[((sq - 8)*4 + d2)*128 + f4*4] =
                make_float4(acc[d2][0], acc[d2][1], acc[d2][2], acc[d2][3]);
    }
    __syncthreads();
    if (sq < 8) {
#pragma unroll
        for (int d2 = 0; d2 < 4; d2++) {
            float4 p4 = *(const float4*)&redB[(sq*4 + d2)*128 + f4*4];
            *(float4*)&redB[(sq*4 + d2)*128 + f4*4] =
                make_float4(acc[d2][0]+p4.x, acc[d2][1]+p4.y, acc[d2][2]+p4.z, acc[d2][3]+p4.w);
        }
    }
    __syncthreads();

    // finalize m2 in registers, BN partials -> global slots
    float m2v;
    {
        int d2 = t >> 7, o = t & 127;
        m2v = linb[l*FD + o];
#pragma unroll
        for (int cc = 0; cc < 8; cc++) m2v += redB[(cc*4 + d2)*128 + o];
        if (MODE == 2) ws[OFF_M2 + (size_t)(dstbase + d2)*FD + o] = m2v;
        atomicAdd(&r1[o], m2v);
        atomicAdd(&r2[o], m2v*m2v);
    }
    __syncthreads();
    if (t < 128) {
        int slot = bid & 7;   // XCD id -> atomics stay XCD-local
        atomicAdd(&ws[OFF_SUMS + l*2048 + slot*256 + t],       r1[t]);
        atomicAdd(&ws[OFF_SUMS + l*2048 + slot*256 + 128 + t], r2[t]);
    }
    if (MODE == 2) return;   // fallback path: BN applied by k_qs / k_bnout

    // ticket barrier (cooperative launch guarantees co-residency).
    // Order: this block's SUMS adds drain before its ticket.
    asm volatile("s_waitcnt vmcnt(0)" ::: "memory");
    __syncthreads();
    if (t == 0) {
        int* ctr = (int*)(ws + OFF_CTR) + l;
        atomicAdd(ctr, 1);
        while (atomicAdd(ctr, 0) < 512) __builtin_amdgcn_s_sleep(8);
    }
    __syncthreads();

    // epilogue: BN(l) scale/shift from SUMS via atomic reads (RMW is
    // coherence-point safe), then BN-apply own 4 rows from registers.
    if (t < 128) {
        float s0 = 0.f, s1 = 0.f;
#pragma unroll
        for (int sl = 0; sl < 8; sl++) {
            s0 += atomicAdd(&ws[OFF_SUMS + l*2048 + sl*256 + t],       0.f);
            s1 += atomicAdd(&ws[OFF_SUMS + l*2048 + sl*256 + 128 + t], 0.f);
        }
        float mu  = s0 * (1.f/2048.f);
        float var = s1 * (1.f/2048.f) - mu*mu;
        float rs  = rsqrtf(var + 1e-5f);
        float gm  = gamma[l*FD + t], bt = beta[l*FD + t];
        sc2[t] = gm * rs;
        sh2[t] = bt - mu * gm * rs;
    }
    __syncthreads();
    {
        int d2 = t >> 7, o = t & 127;
        float xnew = xold + m2v*sc2[o] + sh2[o];
        if (MODE == 0) {
            ws[OFF_X + (size_t)(dstbase + d2)*FD + o] = xnew;   // x_{l+1}
            float p0 = xnew * ws[OFF_QH + (l+1)*256 + o];
            float p1 = xnew * ws[OFF_QH + (l+1)*256 + 128 + o];
            float p2 = xnew * ws[OFF_KH + (l+1)*256 + o];
            float p3 = xnew * ws[OFF_KH + (l+1)*256 + 128 + o];
            for (int off = 32; off; off >>= 1) {
                p0 += __shfl_xor(p0, off, 64);
                p1 += __shfl_xor(p1, off, 64);
                p2 += __shfl_xor(p2, off, 64);
                p3 += __shfl_xor(p3, off, 64);
            }
            int lane = t & 63, wh = (t >> 6) & 1;
            if (lane == 0) {
                redq[d2][wh*4+0] = p0; redq[d2][wh*4+1] = p1;
                redq[d2][wh*4+2] = p2; redq[d2][wh*4+3] = p3;
            }
        } else {
            int n = dstbase + d2, gg = n >> 9, ii = n & 511;
            int off2 = (ii < 256) ? (gg*32768 + o*256 + ii)
                                  : (131072 + gg*32768 + o*256 + (ii - 256));
            out[off2] = xnew;
        }
    }
    if (MODE == 0) {
        __syncthreads();
        if (t < 16) {
            int r = t >> 2, j = t & 3;
            float v = redq[r][j] + redq[r][4+j];
            int n = dstbase + r;
            if      (j == 0) ws[OFF_QS + n] = v;
            else if (j == 1) ws[OFF_QS + NN + n] = v;
            else if (j == 2) ws[OFF_KS + n] = v;
            else             ws[OFF_KS + NN + n] = v;
        }
    }
}

// ---------------- k_qs (fallback): BN(l-1) apply + residual + qs/ks(l)
__global__ __launch_bounds__(512, 4) void k_qs(
    const float* __restrict__ gamma, const float* __restrict__ beta,
    float* __restrict__ ws, int l)
{
    __shared__ float scale[FD], shift[FD];
    __shared__ float red[4][8];
    int bid = blockIdx.x, t = threadIdx.x;
    int lp = l - 1;
    if (t < 128) {
        float s0 = 0.f, s1 = 0.f;
#pragma unroll
        for (int sl = 0; sl < 8; sl++) {
            s0 += ws[OFF_SUMS + lp*2048 + sl*256 + t];
            s1 += ws[OFF_SUMS + lp*2048 + sl*256 + 128 + t];
        }
        float mu  = s0 * (1.f/2048.f);
        float var = s1 * (1.f/2048.f) - mu*mu;
        float rs  = rsqrtf(var + 1e-5f);
        float gm  = gamma[lp*FD + t], bt = beta[lp*FD + t];
        scale[t] = gm * rs;
        shift[t] = bt - mu * gm * rs;
    }
    __syncthreads();
    int n0 = swizzle_n0(bid);
    int row = t >> 7, f = t & 127;
    size_t e = (size_t)(n0 + row)*FD + f;
    float xv = ws[OFF_X + e] + ws[OFF_M2 + e]*scale[f] + shift[f];
    ws[OFF_X + e] = xv;
    float p0 = xv * ws[OFF_QH + l*256 + f];
    float p1 = xv * ws[OFF_QH + l*256 + 128 + f];
    float p2 = xv * ws[OFF_KH + l*256 + f];
    float p3 = xv * ws[OFF_KH + l*256 + 128 + f];
    for (int off = 32; off; off >>= 1) {
        p0 += __shfl_xor(p0, off, 64);
        p1 += __shfl_xor(p1, off, 64);
        p2 += __shfl_xor(p2, off, 64);
        p3 += __shfl_xor(p3, off, 64);
    }
    int lane = t & 63, wh = (t >> 6) & 1;
    if (lane == 0) {
        red[row][wh*4+0] = p0; red[row][wh*4+1] = p1;
        red[row][wh*4+2] = p2; red[row][wh*4+3] = p3;
    }
    __syncthreads();
    if (t < 16) {
        int r = t >> 2, j = t & 3;
        float v = red[r][j] + red[r][4+j];
        int n = n0 + r;
        if      (j == 0) ws[OFF_QS + n] = v;
        else if (j == 1) ws[OFF_QS + NN + n] = v;
        else if (j == 2) ws[OFF_KS + n] = v;
        else             ws[OFF_KS + NN + n] = v;
    }
}

// ---------------- k_bnout (fallback): final BN + residual + output transpose
__global__ __launch_bounds__(256) void k_bnout(
    const float* __restrict__ gamma, const float* __restrict__ beta,
    float* __restrict__ ws, float* __restrict__ out)
{
    __shared__ float scale[FD], shift[FD];
    int bid = blockIdx.x, t = threadIdx.x;
    if (t < 128) {
        float s0 = 0.f, s1 = 0.f;
#pragma unroll
        for (int sl = 0; sl < 8; sl++) {
            s0 += ws[OFF_SUMS + 2*2048 + sl*256 + t];
            s1 += ws[OFF_SUMS + 2*2048 + sl*256 + 128 + t];
        }
        float mu  = s0 * (1.f/2048.f);
        float var = s1 * (1.f/2048.f) - mu*mu;
        float rs  = rsqrtf(var + 1e-5f);
        float gm  = gamma[2*FD + t], bt = beta[2*FD + t];
        scale[t] = gm * rs;
        shift[t] = bt - mu * gm * rs;
    }
    __syncthreads();
#pragma unroll
    for (int i = 0; i < 2; i++) {
        int idx = bid*512 + i*256 + t;
        int f = idx & 127, n = idx >> 7;
        float v = ws[OFF_X + idx] + ws[OFF_M2 + idx]*scale[f] + shift[f];
        int gg = n >> 9, ii = n & 511;
        int off = (ii < 256) ? (gg*32768 + f*256 + ii)
                             : (131072 + gg*32768 + f*256 + (ii - 256));
        out[off] = v;
    }
}

extern "C" void kernel_launch(void* const* d_in, const int* in_sizes, int n_in,
                              void* d_out, int out_size, void* d_ws, size_t ws_size,
                              hipStream_t stream) {
    (void)in_sizes; (void)n_in; (void)out_size; (void)ws_size;
    const float* desc0 = (const float*)d_in[0];
    const float* desc1 = (const float*)d_in[1];
    const float* W     = (const float*)d_in[2];
    const float* q     = (const float*)d_in[3];
    const float* kk    = (const float*)d_in[4];
    const float* convb = (const float*)d_in[5];
    const float* linW  = (const float*)d_in[6];
    const float* linb  = (const float*)d_in[7];
    const float* gamma = (const float*)d_in[8];
    const float* beta  = (const float*)d_in[9];
    float* ws  = (float*)d_ws;
    float* out = (float*)d_out;

    // One-time: can 512 blocks of the fused kernel be co-resident? (pure host
    // queries — no allocation/sync; safe under graph capture)
    static int g_fused = -1;
    if (g_fused < 0) {
        int nb = 0, ncu = 0, dev = 0;
        hipError_t e1 = hipOccupancyMaxActiveBlocksPerMultiprocessor(
            &nb, reinterpret_cast<const void*>(&k_attn<0>), 512, 0);
        hipDeviceProp_t prop;
        if (hipGetDevice(&dev) == hipSuccess &&
            hipGetDeviceProperties(&prop, dev) == hipSuccess)
            ncu = prop.multiProcessorCount;
        g_fused = (e1 == hipSuccess && nb > 0 && ncu > 0 && nb * ncu >= 512) ? 1 : 0;
    }

    hipLaunchKernelGGL(k_pre, dim3(537), dim3(512), 0, stream,
                       desc0, desc1, W, q, kk, linW, ws);

    if (g_fused) {
        static int Ls[3] = {0, 1, 2};
        void* a0[] = {(void*)&W, (void*)&convb, (void*)&linb, (void*)&gamma,
                      (void*)&beta, (void*)&out, (void*)&ws, (void*)&Ls[0]};
        void* a1[] = {(void*)&W, (void*)&convb, (void*)&linb, (void*)&gamma,
                      (void*)&beta, (void*)&out, (void*)&ws, (void*)&Ls[1]};
        void* a2[] = {(void*)&W, (void*)&convb, (void*)&linb, (void*)&gamma,
                      (void*)&beta, (void*)&out, (void*)&ws, (void*)&Ls[2]};
        hipLaunchCooperativeKernel(reinterpret_cast<const void*>(&k_attn<0>),
                                   dim3(512), dim3(512), a0, 0, stream);
        hipLaunchCooperativeKernel(reinterpret_cast<const void*>(&k_attn<0>),
                                   dim3(512), dim3(512), a1, 0, stream);
        hipLaunchCooperativeKernel(reinterpret_cast<const void*>(&k_attn<1>),
                                   dim3(512), dim3(512), a2, 0, stream);
    } else {
        hipLaunchKernelGGL((k_attn<2>), dim3(512), dim3(512), 0, stream,
                           W, convb, linb, gamma, beta, out, ws, 0);
        hipLaunchKernelGGL(k_qs, dim3(512), dim3(512), 0, stream, gamma, beta, ws, 1);
        hipLaunchKernelGGL((k_attn<2>), dim3(512), dim3(512), 0, stream,
                           W, convb, linb, gamma, beta, out, ws, 1);
        hipLaunchKernelGGL(k_qs, dim3(512), dim3(512), 0, stream, gamma, beta, ws, 2);
        hipLaunchKernelGGL((k_attn<2>), dim3(512), dim3(512), 0, stream,
                           W, convb, linb, gamma, beta, out, ws, 2);
        hipLaunchKernelGGL(k_bnout, dim3(512), dim3(256), 0, stream,
                           gamma, beta, ws, out);
    }
}

// Round 8
// 168.797 us; speedup vs baseline: 1.0236x; 1.0236x over previous
//
#include <hip/hip_runtime.h>

#define FD  128
#define NN  2048

// workspace layout (float elements). In fused mode m2 never materialized
// (lives in regs between the m2 GEMM and the fused BN epilogue).
#define OFF_X     0            // x[n][f] (BN-applied, updated per layer)
#define OFF_QS    262144       // qs[r][n]           2*2048
#define OFF_KS    266240       // ks[r][n]           2*2048
#define OFF_SUMS  270336       // l*2048 + slot*256 + {0:sum,128:sumsq}, 8 slots
#define OFF_CTR   276480       // l*16 + {0..7: per-slot ctr, 8: global ctr} ints
#define OFF_LWT   276608       // l*32768 + c*128 + o   (lin_W transposed)
#define OFF_QH    374912       // qhat[l][r][f] = sum_o W[l,r,f,o]*q[l,o]  768
#define OFF_KH    375680       // khat[l][r][f]                            768
#define OFF_M2    376448       // m2[n][f] (fallback path only)

// XCD-affine swizzle for 512 blocks: bid&7 = XCD; graph = XCD pair; 128
// slots x 4 rows per graph.
__device__ __forceinline__ int swizzle_n0(int bid) {
    int g    = (bid & 7) >> 1;                 // graph 0..3
    int slot = ((bid >> 3) << 1) | (bid & 1);  // 0..127
    return g*512 + slot*4;                     // first of 4 rows
}

// layer-0 qs/ks via full proj in registers. No proj store.
__device__ __forceinline__ void qsks0(
    const float* __restrict__ W, const float* __restrict__ qv,
    const float* __restrict__ kv, float* __restrict__ ws,
    int n0, int t, const float (*xs)[FD],
    float (*redp)[256], float* red)
{
    int kh = t >> 8, tp = t & 255;
    int rsel = tp >> 7, o = tp & 127;
    const float* Wl = W + ((size_t)rsel*FD)*FD + o;
    float acc[4];
#pragma unroll
    for (int r = 0; r < 4; r++) acc[r] = 0.f;
    int kbase = kh * 64;
#pragma unroll
    for (int kk = 0; kk < 64; kk += 4) {
        int k4 = kbase + kk;
        float w0 = Wl[(k4+0)*FD], w1 = Wl[(k4+1)*FD];
        float w2 = Wl[(k4+2)*FD], w3 = Wl[(k4+3)*FD];
#pragma unroll
        for (int r = 0; r < 4; r++) {
            float4 xq = *(const float4*)&xs[r][k4];
            acc[r] += xq.x*w0 + xq.y*w1 + xq.z*w2 + xq.w*w3;
        }
    }
    if (kh == 1) {
#pragma unroll
        for (int r = 0; r < 4; r++) redp[r][tp] = acc[r];
    }
    __syncthreads();
    if (t < 256) {
#pragma unroll
        for (int r = 0; r < 4; r++) acc[r] += redp[r][tp];
        float qq = qv[o], kq = kv[o];
        int lane = t & 63, w = t >> 6;
#pragma unroll
        for (int r = 0; r < 4; r++) {
            float vq = acc[r]*qq, vk = acc[r]*kq;
            for (int off = 32; off; off >>= 1) {
                vq += __shfl_xor(vq, off, 64);
                vk += __shfl_xor(vk, off, 64);
            }
            if (lane == 0) { red[w*8 + r*2] = vq; red[w*8 + r*2 + 1] = vk; }
        }
    }
    __syncthreads();
    if (t < 16) {
        int r = t & 3, rs = (t >> 2) & 1, wh = t >> 3;
        float v = red[(rs*2)*8 + r*2 + wh] + red[(rs*2 + 1)*8 + r*2 + wh];
        if (wh == 0) ws[OFF_QS + rs*NN + n0 + r] = v;
        else         ws[OFF_KS + rs*NN + n0 + r] = v;
    }
}

// ---------------- k_pre: transpose + qs/ks(0) + linWT + qhat/khat + zero sums/ctrs
__global__ __launch_bounds__(512, 4) void k_pre(
    const float* __restrict__ d0, const float* __restrict__ d1,
    const float* __restrict__ W,  const float* __restrict__ qv,
    const float* __restrict__ kv, const float* __restrict__ linW,
    float* __restrict__ ws)
{
    int bid = blockIdx.x, t = threadIdx.x;
    if (bid >= 512) {
        if (bid < 536) {               // linWT[l][c][o] = lin_W[l][o][c]
            int vb = bid - 512;        // 0..23
#pragma unroll
            for (int i = 0; i < 8; i++) {
                int e = vb*4096 + i*512 + t;   // 0..98303
                int l = e >> 15, rem = e & 32767;
                int o = rem >> 8, c = rem & 255;
                ws[OFF_LWT + l*32768 + c*FD + o] = linW[e];
            }
        } else {                       // bid 536: zero sums+ctrs, qhat/khat
            for (int i = t; i < 6144 + 128; i += 512) ws[OFF_SUMS + i] = 0.f;
#pragma unroll
            for (int ii = 0; ii < 3; ii++) {
                int e = ii*512 + t;            // 0..1535
                int sel = e & 1, idx = e >> 1; // idx = l*256 + r*128 + f
                const float* wrow = W + (size_t)idx*FD;
                int l = idx >> 8;
                const float* vvec = sel ? (kv + l*FD) : (qv + l*FD);
                float acc = 0.f;
                for (int o = 0; o < FD; o++) acc += wrow[o]*vvec[o];
                ws[(sel ? OFF_KH : OFF_QH) + idx] = acc;
            }
        }
        return;
    }
    __shared__ __attribute__((aligned(16))) float xs[4][FD];
    __shared__ float redp[4][256];
    __shared__ float red[32];
    int n0 = swizzle_n0(bid);
    {
        int row = t >> 7, f = t & 127;
        int n = n0 + row, gg = n >> 9, ii = n & 511;
        float v = (ii < 256) ? d0[gg*32768 + f*256 + ii]
                             : d1[gg*32768 + f*256 + (ii - 256)];
        xs[row][f] = v;
        ws[OFF_X + (size_t)n*FD + f] = v;
    }
    __syncthreads();
    qsks0(W, qv, kv, ws, n0, t, xs, redp, red);
}

// ---------------- k_attn<MODE>: stats + att-sum + agg GEMM + m1 + m2 GEMM.
// MODE 0: fused epilogue writes x_{l+1} + qs/ks(l+1)  [cooperative launch]
// MODE 1: fused epilogue writes final output          [cooperative launch]
// MODE 2: no epilogue; write m2 to global (fallback, normal launch)
// Intra-kernel sync (MODE 0/1): hierarchical ticket barrier (atomics only
// for the ~72 arrival RMWs; spin + SUMS readback use device-scope LOADS,
// which don't serialize at the coherence point — R7 lesson).
template<int MODE>
__global__ __launch_bounds__(512, 4) void k_attn(
    const float* __restrict__ Wg,    const float* __restrict__ convb,
    const float* __restrict__ linb,  const float* __restrict__ gamma,
    const float* __restrict__ beta,  float* __restrict__ out,
    float* __restrict__ ws, int l)
{
    __shared__ __attribute__((aligned(16))) float att[4*512];    // 8K
    __shared__ __attribute__((aligned(16))) float redB[8*4*128]; // 16K
    __shared__ __attribute__((aligned(16))) float hgc[4*256];    // hg -> cat 4K
    __shared__ float sml[4][2], sls[4][2];
    __shared__ float r1[FD], r2[FD];
    __shared__ float sc2[FD], sh2[FD];
    __shared__ float redq[4][8];

    int bid = blockIdx.x, t = threadIdx.x;
    int dstbase = swizzle_n0(bid);
    int g = dstbase >> 9, dloc0 = dstbase & 511;
    int Gd = (dloc0 >= 256) ? 1 : 0;

    // stats: 8 waves, 2 per dst row (half src-range each), merged via LDS
    {
        int w = t >> 6, p = t & 63;
        int d = w >> 1, h = w & 1;
        int dloc = dloc0 + d;
        float q0 = ws[OFF_QS + dstbase + d];
        float q1 = ws[OFF_QS + NN + dstbase + d];
        float sc[4];
#pragma unroll
        for (int j = 0; j < 4; j++) {
            int s = h*256 + p + j*64;
            int ts = (s < 256) ? Gd : 1 - Gd;
            float a = (ts ? q1 : q0) + ws[OFF_KS + ts*NN + g*512 + s];
            a = a > 0.f ? a : 0.2f*a;
            sc[j] = (s == dloc) ? -1e30f : a;
        }
        float lm = fmaxf(fmaxf(sc[0], sc[1]), fmaxf(sc[2], sc[3]));
        for (int off = 32; off; off >>= 1) lm = fmaxf(lm, __shfl_xor(lm, off, 64));
        float ex[4], lsum = 0.f;
#pragma unroll
        for (int j = 0; j < 4; j++) { ex[j] = __expf(sc[j] - lm); lsum += ex[j]; }
        for (int off = 32; off; off >>= 1) lsum += __shfl_xor(lsum, off, 64);
#pragma unroll
        for (int j = 0; j < 4; j++) att[d*512 + h*256 + p + j*64] = ex[j];
        if (p == 0) { sml[d][h] = lm; sls[d][h] = lsum; }
    }
    __syncthreads();
    // normalize across the two halves + zero r1/r2
    {
        int d = t >> 7, s4 = (t & 127) * 4;
        int h = (s4 >= 256) ? 1 : 0;
        float m0 = sml[d][0], m1 = sml[d][1];
        float M = fmaxf(m0, m1);
        float denom = sls[d][0]*__expf(m0 - M) + sls[d][1]*__expf(m1 - M) + 1e-16f;
        float fac = __expf(sml[d][h] - M) / denom;
        float4 a4 = *(float4*)&att[d*512 + s4];
        a4.x *= fac; a4.y *= fac; a4.z *= fac; a4.w *= fac;
        *(float4*)&att[d*512 + s4] = a4;
        if (t < 128) r1[t] = 0.f;
        else if (t < 256) r2[t - 128] = 0.f;
    }
    __syncthreads();

    // phase B: att-weighted sums of x by src half; 2-deep register pipeline.
    int f4 = t & 31, sq = t >> 5;
    float acc[4][4];
#pragma unroll
    for (int d2 = 0; d2 < 4; d2++)
#pragma unroll
        for (int j = 0; j < 4; j++) acc[d2][j] = 0.f;
    {
        const float* xp = ws + OFF_X + (size_t)(g*512)*FD + f4*4;
        int s0 = sq * 32;
        float4 bufA[4], bufB[4];
#pragma unroll
        for (int u = 0; u < 4; u++) bufA[u] = *(const float4*)&xp[(size_t)(s0+u)*FD];
#pragma unroll
        for (int ii = 0; ii < 8; ii++) {
            const float4* cur = (ii & 1) ? bufB : bufA;   // static under unroll
            float4*       nxt = (ii & 1) ? bufA : bufB;
            if (ii < 7) {
#pragma unroll
                for (int u = 0; u < 4; u++)
                    nxt[u] = *(const float4*)&xp[(size_t)(s0 + (ii+1)*4 + u)*FD];
            }
#pragma unroll
            for (int u = 0; u < 4; u++) {
                int s = s0 + ii*4 + u;
                float4 v = cur[u];
#pragma unroll
                for (int d2 = 0; d2 < 4; d2++) {
                    float b = att[d2*512 + s];
                    acc[d2][0] += b*v.x; acc[d2][1] += b*v.y;
                    acc[d2][2] += b*v.z; acc[d2][3] += b*v.w;
                }
            }
        }
    }
    // group-split staged reduction: slots 0..3 = src half0, 4..7 = half1
    {
        int slot = (sq & 3) + ((sq >> 3) << 2);
        if (sq & 4) {
#pragma unroll
            for (int d2 = 0; d2 < 4; d2++)
                *(float4*)&redB[(slot*4 + d2)*128 + f4*4] =
                    make_float4(acc[d2][0], acc[d2][1], acc[d2][2], acc[d2][3]);
        }
        __syncthreads();
        if (!(sq & 4)) {
#pragma unroll
            for (int d2 = 0; d2 < 4; d2++) {
                float4 p4 = *(const float4*)&redB[(slot*4 + d2)*128 + f4*4];
                *(float4*)&redB[(slot*4 + d2)*128 + f4*4] =
                    make_float4(acc[d2][0]+p4.x, acc[d2][1]+p4.y, acc[d2][2]+p4.z, acc[d2][3]+p4.w);
            }
        }
        __syncthreads();
    }
    // hg reduce -> hgc = [hg_same | hg_cross]
    {
        int d2 = t >> 7, f = t & 127;
        float hg0 = redB[(0*4+d2)*128+f] + redB[(1*4+d2)*128+f]
                  + redB[(2*4+d2)*128+f] + redB[(3*4+d2)*128+f];
        float hg1 = redB[(4*4+d2)*128+f] + redB[(5*4+d2)*128+f]
                  + redB[(6*4+d2)*128+f] + redB[(7*4+d2)*128+f];
        hgc[d2*256 + f]       = Gd ? hg1 : hg0;   // same-group (rel 0)
        hgc[d2*256 + 128 + f] = Gd ? hg0 : hg1;   // cross-group (rel 1)
    }
    __syncthreads();

    // agg GEMM: [4,256] x Wcat[256,128]
#pragma unroll
    for (int d2 = 0; d2 < 4; d2++)
#pragma unroll
        for (int j = 0; j < 4; j++) acc[d2][j] = 0.f;
    {
        int rel = sq >> 3;
        const float* wp = Wg + ((size_t)((l*2 + rel)*FD) + (sq & 7)*16)*FD + f4*4;
        int c0 = sq * 16;
        float4 wA[4], wB[4];
#pragma unroll
        for (int u = 0; u < 4; u++) wA[u] = *(const float4*)&wp[(size_t)u*FD];
#pragma unroll
        for (int ii = 0; ii < 4; ii++) {
            const float4* cur = (ii & 1) ? wB : wA;
            float4*       nxt = (ii & 1) ? wA : wB;
            if (ii < 3) {
#pragma unroll
                for (int u = 0; u < 4; u++)
                    nxt[u] = *(const float4*)&wp[(size_t)((ii+1)*4 + u)*FD];
            }
#pragma unroll
            for (int u = 0; u < 4; u++) {
                int c = c0 + ii*4 + u;
                float4 w4 = cur[u];
#pragma unroll
                for (int d2 = 0; d2 < 4; d2++) {
                    float cv = hgc[d2*256 + c];
                    acc[d2][0] += cv*w4.x; acc[d2][1] += cv*w4.y;
                    acc[d2][2] += cv*w4.z; acc[d2][3] += cv*w4.w;
                }
            }
        }
    }
    if (sq >= 8) {
#pragma unroll
        for (int d2 = 0; d2 < 4; d2++)
            *(float4*)&redB[((sq - 8)*4 + d2)*128 + f4*4] =
                make_float4(acc[d2][0], acc[d2][1], acc[d2][2], acc[d2][3]);
    }
    __syncthreads();
    if (sq < 8) {
#pragma unroll
        for (int d2 = 0; d2 < 4; d2++) {
            float4 p4 = *(const float4*)&redB[(sq*4 + d2)*128 + f4*4];
            *(float4*)&redB[(sq*4 + d2)*128 + f4*4] =
                make_float4(acc[d2][0]+p4.x, acc[d2][1]+p4.y, acc[d2][2]+p4.z, acc[d2][3]+p4.w);
        }
    }
    __syncthreads();

    // agg reduce -> m1; build cat = [x | m1]; capture x_old in reg
    float xold;
    {
        int d2 = t >> 7, f = t & 127;
        float agg = 0.f;
#pragma unroll
        for (int cc = 0; cc < 8; cc++) agg += redB[(cc*4 + d2)*128 + f];
        float m1v = fmaxf(agg + convb[l*FD + f], 0.f);
        hgc[d2*256 + 128 + f] = m1v;
        xold = ws[OFF_X + (size_t)(dstbase + d2)*FD + f];
        hgc[d2*256 + f] = xold;
    }
    __syncthreads();

    // m2 GEMM: [4,256] x linWT[256,128]
#pragma unroll
    for (int d2 = 0; d2 < 4; d2++)
#pragma unroll
        for (int j = 0; j < 4; j++) acc[d2][j] = 0.f;
    {
        const float* lwt = ws + OFF_LWT + l*32768 + f4*4;
        int c0 = sq * 16;
        float4 wA[4], wB[4];
#pragma unroll
        for (int u = 0; u < 4; u++) wA[u] = *(const float4*)&lwt[(c0+u)*128];
#pragma unroll
        for (int ii = 0; ii < 4; ii++) {
            const float4* cur = (ii & 1) ? wB : wA;
            float4*       nxt = (ii & 1) ? wA : wB;
            if (ii < 3) {
#pragma unroll
                for (int u = 0; u < 4; u++)
                    nxt[u] = *(const float4*)&lwt[(c0 + (ii+1)*4 + u)*128];
            }
#pragma unroll
            for (int u = 0; u < 4; u++) {
                int c = c0 + ii*4 + u;
                float4 w4 = cur[u];
#pragma unroll
                for (int d2 = 0; d2 < 4; d2++) {
                    float cv = hgc[d2*256 + c];
                    acc[d2][0] += cv*w4.x; acc[d2][1] += cv*w4.y;
                    acc[d2][2] += cv*w4.z; acc[d2][3] += cv*w4.w;
                }
            }
        }
    }
    if (sq >= 8) {
#pragma unroll
        for (int d2 = 0; d2 < 4; d2++)
            *(float4*)&redB[((sq - 8)*4 + d2)*128 + f4*4] =
                make_float4(acc[d2][0], acc[d2][1], acc[d2][2], acc[d2][3]);
    }
    __syncthreads();
    if (sq < 8) {
#pragma unroll
        for (int d2 = 0; d2 < 4; d2++) {
            float4 p4 = *(const float4*)&redB[(sq*4 + d2)*128 + f4*4];
            *(float4*)&redB[(sq*4 + d2)*128 + f4*4] =
                make_float4(acc[d2][0]+p4.x, acc[d2][1]+p4.y, acc[d2][2]+p4.z, acc[d2][3]+p4.w);
        }
    }
    __syncthreads();

    // finalize m2 in registers, BN partials -> global slots
    float m2v;
    {
        int d2 = t >> 7, o = t & 127;
        m2v = linb[l*FD + o];
#pragma unroll
        for (int cc = 0; cc < 8; cc++) m2v += redB[(cc*4 + d2)*128 + o];
        if (MODE == 2) ws[OFF_M2 + (size_t)(dstbase + d2)*FD + o] = m2v;
        atomicAdd(&r1[o], m2v);
        atomicAdd(&r2[o], m2v*m2v);
    }
    __syncthreads();
    if (t < 128) {
        int slot = bid & 7;   // XCD id -> atomics stay XCD-local
        atomicAdd(&ws[OFF_SUMS + l*2048 + slot*256 + t],       r1[t]);
        atomicAdd(&ws[OFF_SUMS + l*2048 + slot*256 + 128 + t], r2[t]);
    }
    if (MODE == 2) return;   // fallback path: BN applied by k_qs / k_bnout

    // hierarchical ticket barrier (cooperative launch guarantees residency).
    // Order: this block's SUMS adds drain before its ticket. Arrivals are the
    // only RMWs (~72 serialized); the spin is a device-scope LOAD (no
    // coherence-point serialization — R7's 45us lesson).
    asm volatile("s_waitcnt vmcnt(0)" ::: "memory");
    __syncthreads();
    if (t == 0) {
        int* ctrs = (int*)(ws + OFF_CTR) + l*16;
        int old = atomicAdd(ctrs + (bid & 7), 1);
        if (old == 63) atomicAdd(ctrs + 8, 1);   // last arrival of this slot
        while (__hip_atomic_load(ctrs + 8, __ATOMIC_ACQUIRE,
                                 __HIP_MEMORY_SCOPE_AGENT) < 8)
            __builtin_amdgcn_s_sleep(16);
    }
    __syncthreads();

    // epilogue: BN(l) scale/shift from SUMS via device-scope loads (cache-
    // bypassing per HIP memory model; no RMW), then BN-apply from registers.
    if (t < 128) {
        float s0 = 0.f, s1 = 0.f;
#pragma unroll
        for (int sl = 0; sl < 8; sl++) {
            s0 += __hip_atomic_load(&ws[OFF_SUMS + l*2048 + sl*256 + t],
                                    __ATOMIC_RELAXED, __HIP_MEMORY_SCOPE_AGENT);
            s1 += __hip_atomic_load(&ws[OFF_SUMS + l*2048 + sl*256 + 128 + t],
                                    __ATOMIC_RELAXED, __HIP_MEMORY_SCOPE_AGENT);
        }
        float mu  = s0 * (1.f/2048.f);
        float var = s1 * (1.f/2048.f) - mu*mu;
        float rs  = rsqrtf(var + 1e-5f);
        float gm  = gamma[l*FD + t], bt = beta[l*FD + t];
        sc2[t] = gm * rs;
        sh2[t] = bt - mu * gm * rs;
    }
    __syncthreads();
    {
        int d2 = t >> 7, o = t & 127;
        float xnew = xold + m2v*sc2[o] + sh2[o];
        if (MODE == 0) {
            ws[OFF_X + (size_t)(dstbase + d2)*FD + o] = xnew;   // x_{l+1}
            float p0 = xnew * ws[OFF_QH + (l+1)*256 + o];
            float p1 = xnew * ws[OFF_QH + (l+1)*256 + 128 + o];
            float p2 = xnew * ws[OFF_KH + (l+1)*256 + o];
            float p3 = xnew * ws[OFF_KH + (l+1)*256 + 128 + o];
            for (int off = 32; off; off >>= 1) {
                p0 += __shfl_xor(p0, off, 64);
                p1 += __shfl_xor(p1, off, 64);
                p2 += __shfl_xor(p2, off, 64);
                p3 += __shfl_xor(p3, off, 64);
            }
            int lane = t & 63, wh = (t >> 6) & 1;
            if (lane == 0) {
                redq[d2][wh*4+0] = p0; redq[d2][wh*4+1] = p1;
                redq[d2][wh*4+2] = p2; redq[d2][wh*4+3] = p3;
            }
        } else {
            int n = dstbase + d2, gg = n >> 9, ii = n & 511;
            int off2 = (ii < 256) ? (gg*32768 + o*256 + ii)
                                  : (131072 + gg*32768 + o*256 + (ii - 256));
            out[off2] = xnew;
        }
    }
    if (MODE == 0) {
        __syncthreads();
        if (t < 16) {
            int r = t >> 2, j = t & 3;
            float v = redq[r][j] + redq[r][4+j];
            int n = dstbase + r;
            if      (j == 0) ws[OFF_QS + n] = v;
            else if (j == 1) ws[OFF_QS + NN + n] = v;
            else if (j == 2) ws[OFF_KS + n] = v;
            else             ws[OFF_KS + NN + n] = v;
        }
    }
}

// ---------------- k_qs (fallback): BN(l-1) apply + residual + qs/ks(l)
__global__ __launch_bounds__(512, 4) void k_qs(
    const float* __restrict__ gamma, const float* __restrict__ beta,
    float* __restrict__ ws, int l)
{
    __shared__ float scale[FD], shift[FD];
    __shared__ float red[4][8];
    int bid = blockIdx.x, t = threadIdx.x;
    int lp = l - 1;
    if (t < 128) {
        float s0 = 0.f, s1 = 0.f;
#pragma unroll
        for (int sl = 0; sl < 8; sl++) {
            s0 += ws[OFF_SUMS + lp*2048 + sl*256 + t];
            s1 += ws[OFF_SUMS + lp*2048 + sl*256 + 128 + t];
        }
        float mu  = s0 * (1.f/2048.f);
        float var = s1 * (1.f/2048.f) - mu*mu;
        float rs  = rsqrtf(var + 1e-5f);
        float gm  = gamma[lp*FD + t], bt = beta[lp*FD + t];
        scale[t] = gm * rs;
        shift[t] = bt - mu * gm * rs;
    }
    __syncthreads();
    int n0 = swizzle_n0(bid);
    int row = t >> 7, f = t & 127;
    size_t e = (size_t)(n0 + row)*FD + f;
    float xv = ws[OFF_X + e] + ws[OFF_M2 + e]*scale[f] + shift[f];
    ws[OFF_X + e] = xv;
    float p0 = xv * ws[OFF_QH + l*256 + f];
    float p1 = xv * ws[OFF_QH + l*256 + 128 + f];
    float p2 = xv * ws[OFF_KH + l*256 + f];
    float p3 = xv * ws[OFF_KH + l*256 + 128 + f];
    for (int off = 32; off; off >>= 1) {
        p0 += __shfl_xor(p0, off, 64);
        p1 += __shfl_xor(p1, off, 64);
        p2 += __shfl_xor(p2, off, 64);
        p3 += __shfl_xor(p3, off, 64);
    }
    int lane = t & 63, wh = (t >> 6) & 1;
    if (lane == 0) {
        red[row][wh*4+0] = p0; red[row][wh*4+1] = p1;
        red[row][wh*4+2] = p2; red[row][wh*4+3] = p3;
    }
    __syncthreads();
    if (t < 16) {
        int r = t >> 2, j = t & 3;
        float v = red[r][j] + red[r][4+j];
        int n = n0 + r;
        if      (j == 0) ws[OFF_QS + n] = v;
        else if (j == 1) ws[OFF_QS + NN + n] = v;
        else if (j == 2) ws[OFF_KS + n] = v;
        else             ws[OFF_KS + NN + n] = v;
    }
}

// ---------------- k_bnout (fallback): final BN + residual + output transpose
__global__ __launch_bounds__(256) void k_bnout(
    const float* __restrict__ gamma, const float* __restrict__ beta,
    float* __restrict__ ws, float* __restrict__ out)
{
    __shared__ float scale[FD], shift[FD];
    int bid = blockIdx.x, t = threadIdx.x;
    if (t < 128) {
        float s0 = 0.f, s1 = 0.f;
#pragma unroll
        for (int sl = 0; sl < 8; sl++) {
            s0 += ws[OFF_SUMS + 2*2048 + sl*256 + t];
            s1 += ws[OFF_SUMS + 2*2048 + sl*256 + 128 + t];
        }
        float mu  = s0 * (1.f/2048.f);
        float var = s1 * (1.f/2048.f) - mu*mu;
        float rs  = rsqrtf(var + 1e-5f);
        float gm  = gamma[2*FD + t], bt = beta[2*FD + t];
        scale[t] = gm * rs;
        shift[t] = bt - mu * gm * rs;
    }
    __syncthreads();
#pragma unroll
    for (int i = 0; i < 2; i++) {
        int idx = bid*512 + i*256 + t;
        int f = idx & 127, n = idx >> 7;
        float v = ws[OFF_X + idx] + ws[OFF_M2 + idx]*scale[f] + shift[f];
        int gg = n >> 9, ii = n & 511;
        int off = (ii < 256) ? (gg*32768 + f*256 + ii)
                             : (131072 + gg*32768 + f*256 + (ii - 256));
        out[off] = v;
    }
}

extern "C" void kernel_launch(void* const* d_in, const int* in_sizes, int n_in,
                              void* d_out, int out_size, void* d_ws, size_t ws_size,
                              hipStream_t stream) {
    (void)in_sizes; (void)n_in; (void)out_size; (void)ws_size;
    const float* desc0 = (const float*)d_in[0];
    const float* desc1 = (const float*)d_in[1];
    const float* W     = (const float*)d_in[2];
    const float* q     = (const float*)d_in[3];
    const float* kk    = (const float*)d_in[4];
    const float* convb = (const float*)d_in[5];
    const float* linW  = (const float*)d_in[6];
    const float* linb  = (const float*)d_in[7];
    const float* gamma = (const float*)d_in[8];
    const float* beta  = (const float*)d_in[9];
    float* ws  = (float*)d_ws;
    float* out = (float*)d_out;

    // One-time: can 512 blocks of the fused kernel be co-resident? (pure host
    // queries — no allocation/sync; safe under graph capture)
    static int g_fused = -1;
    if (g_fused < 0) {
        int nb = 0, ncu = 0, dev = 0;
        hipError_t e1 = hipOccupancyMaxActiveBlocksPerMultiprocessor(
            &nb, reinterpret_cast<const void*>(&k_attn<0>), 512, 0);
        hipDeviceProp_t prop;
        if (hipGetDevice(&dev) == hipSuccess &&
            hipGetDeviceProperties(&prop, dev) == hipSuccess)
            ncu = prop.multiProcessorCount;
        g_fused = (e1 == hipSuccess && nb > 0 && ncu > 0 && nb * ncu >= 512) ? 1 : 0;
    }

    hipLaunchKernelGGL(k_pre, dim3(537), dim3(512), 0, stream,
                       desc0, desc1, W, q, kk, linW, ws);

    if (g_fused) {
        static int Ls[3] = {0, 1, 2};
        void* a0[] = {(void*)&W, (void*)&convb, (void*)&linb, (void*)&gamma,
                      (void*)&beta, (void*)&out, (void*)&ws, (void*)&Ls[0]};
        void* a1[] = {(void*)&W, (void*)&convb, (void*)&linb, (void*)&gamma,
                      (void*)&beta, (void*)&out, (void*)&ws, (void*)&Ls[1]};
        void* a2[] = {(void*)&W, (void*)&convb, (void*)&linb, (void*)&gamma,
                      (void*)&beta, (void*)&out, (void*)&ws, (void*)&Ls[2]};
        hipLaunchCooperativeKernel(reinterpret_cast<const void*>(&k_attn<0>),
                                   dim3(512), dim3(512), a0, 0, stream);
        hipLaunchCooperativeKernel(reinterpret_cast<const void*>(&k_attn<0>),
                                   dim3(512), dim3(512), a1, 0, stream);
        hipLaunchCooperativeKernel(reinterpret_cast<const void*>(&k_attn<1>),
                                   dim3(512), dim3(512), a2, 0, stream);
    } else {
        hipLaunchKernelGGL((k_attn<2>), dim3(512), dim3(512), 0, stream,
                           W, convb, linb, gamma, beta, out, ws, 0);
        hipLaunchKernelGGL(k_qs, dim3(512), dim3(512), 0, stream, gamma, beta, ws, 1);
        hipLaunchKernelGGL((k_attn<2>), dim3(512), dim3(512), 0, stream,
                           W, convb, linb, gamma, beta, out, ws, 1);
        hipLaunchKernelGGL(k_qs, dim3(512), dim3(512), 0, stream, gamma, beta, ws, 2);
        hipLaunchKernelGGL((k_attn<2>), dim3(512), dim3(512), 0, stream,
                           W, convb, linb, gamma, beta, out, ws, 2);
        hipLaunchKernelGGL(k_bnout, dim3(512), dim3(256), 0, stream,
                           gamma, beta, ws, out);
    }
}